// Round 1
// baseline (403.935 us; speedup 1.0000x reference)
//
#include <hip/hip_runtime.h>
#include <math.h>

// Problem constants (fixed by reference): B=16, L=8, A_CH=2, H=W=384, HID=64
#define HWDIM 384
#define PPX   (HWDIM * HWDIM)   // 147456 pixels per image
#define NBL   128               // B*L
#define NB    16

// ws layout (floats): [0,128) mean_conf_sum  [128,256) overlap_sum  [256,272) demand_sum
#define WS_FLOATS (2 * NBL + NB)

__device__ __forceinline__ float fast_sigmoid(float x) {
    return 1.0f / (1.0f + __expf(-x));
}

// conf at integer source location (yi, xi) of image bl, recomputed from psm.
// conf = sigmoid(max(ch0, ch1)) because sigmoid is monotone.
__device__ __forceinline__ float conf_sample(const float* __restrict__ img0, int yi, int xi) {
    bool valid = ((unsigned)xi < HWDIM) && ((unsigned)yi < HWDIM);
    int yc = min(max(yi, 0), HWDIM - 1);
    int xc = min(max(xi, 0), HWDIM - 1);
    int off = yc * HWDIM + xc;
    float m = fmaxf(img0[off], img0[off + PPX]);
    float v = fast_sigmoid(m);
    return valid ? v : 0.0f;
}

__global__ __launch_bounds__(256) void zero_kernel(float* __restrict__ s) {
    int i = blockIdx.x * blockDim.x + threadIdx.x;
    if (i < WS_FLOATS) s[i] = 0.0f;
}

// One fused pass over psm_single: per (b,l) accumulates
//   sum(conf), sum(Di * bilinear_warp(conf, A)), and (l==0) sum(Di).
__global__ __launch_bounds__(256) void heavy_kernel(
    const float* __restrict__ psm, const float* __restrict__ req,
    const float* __restrict__ naff, float* __restrict__ sums)
{
    const int bl = blockIdx.y;
    const int b = bl >> 3;
    const int l = bl & 7;
    const float* img0   = psm + (size_t)bl * (2 * PPX);
    const float* di_img = req + (size_t)(b * 8) * PPX;   // req[(8b), 0, :, :]

    // Aij = norm_affine[b, 0, l]  -> flat ((b*8+0)*8 + l)*6
    const int abase = (b * 64 + l) * 6;
    const float a00 = naff[abase + 0], a01 = naff[abase + 1], a02 = naff[abase + 2];
    const float a10 = naff[abase + 3], a11 = naff[abase + 4], a12 = naff[abase + 5];

    float s_conf = 0.0f, s_ov = 0.0f, s_di = 0.0f;
    const int stride = blockDim.x * gridDim.x;
    const float step = 2.0f / (float)(HWDIM - 1);
    const float half = 0.5f * (float)(HWDIM - 1);

    for (int p = blockIdx.x * blockDim.x + threadIdx.x; p < PPX; p += stride) {
        int y = p / HWDIM;
        int x = p - y * HWDIM;

        // own-pixel conf (for mean_conf)
        float c0 = img0[p];
        float c1 = img0[p + PPX];
        float conf_own = fast_sigmoid(fmaxf(c0, c1));
        s_conf += conf_own;

        float di = di_img[p];
        s_di += di;

        // affine warp source coords (grid in [-1,1], indexing='ij')
        float gxv = fmaf((float)x, step, -1.0f);
        float gyv = fmaf((float)y, step, -1.0f);
        float sx = a00 * gxv + a01 * gyv + a02;
        float sy = a10 * gxv + a11 * gyv + a12;
        float pxf = (sx + 1.0f) * half;
        float pyf = (sy + 1.0f) * half;
        float x0f = floorf(pxf), y0f = floorf(pyf);
        float wx = pxf - x0f, wy = pyf - y0f;
        int x0 = (int)x0f, y0 = (int)y0f;

        float v00 = conf_sample(img0, y0,     x0);
        float v01 = conf_sample(img0, y0,     x0 + 1);
        float v10 = conf_sample(img0, y0 + 1, x0);
        float v11 = conf_sample(img0, y0 + 1, x0 + 1);

        float warped = v00 * (1.0f - wy) * (1.0f - wx)
                     + v01 * (1.0f - wy) * wx
                     + v10 * wy * (1.0f - wx)
                     + v11 * wy * wx;
        s_ov += di * warped;
    }

    // wave-64 shuffle reduce
    for (int o = 32; o > 0; o >>= 1) {
        s_conf += __shfl_down(s_conf, o);
        s_ov   += __shfl_down(s_ov,   o);
        s_di   += __shfl_down(s_di,   o);
    }
    if ((threadIdx.x & 63) == 0) {
        atomicAdd(&sums[bl], s_conf);
        atomicAdd(&sums[NBL + bl], s_ov);
        if (l == 0) atomicAdd(&sums[2 * NBL + b], s_di);
    }
}

// One block (= one wave of 64) per (b,l): q-MLP, k-MLP, edge-MLP, sigmoid.
__global__ __launch_bounds__(64) void mlp_kernel(
    const float* __restrict__ sums, const float* __restrict__ naff,
    const float* __restrict__ qW1, const float* __restrict__ qb1,
    const float* __restrict__ qW2, const float* __restrict__ qb2,
    const float* __restrict__ kW1, const float* __restrict__ kb1,
    const float* __restrict__ kW2, const float* __restrict__ kb2,
    const float* __restrict__ eW1, const float* __restrict__ eb1,
    const float* __restrict__ eW2, const float* __restrict__ eb2,
    float* __restrict__ out)
{
    const int bl = blockIdx.x;
    const int b = bl >> 3;
    const int l = bl & 7;
    const int t = threadIdx.x;
    const float invP = 1.0f / (float)PPX;

    const float demand = sums[2 * NBL + b] * invP;
    const float mc0    = sums[b * 8] * invP;
    const float mc     = sums[bl] * invP;
    const float ov     = sums[NBL + bl] * invP;

    const int abase = (b * 64 + l) * 6;
    const float dx = naff[abase + 2];
    const float dy = naff[abase + 5];
    const float dist = sqrtf(dx * dx + dy * dy);

    // diag[b,l] = norm_affine[b,l,l] -> flat ((b*8+l)*8+l)*6 = (b*64 + 9l)*6
    const int dbase  = (b * 64 + 9 * l) * 6;
    const int dbase0 = (b * 64) * 6;
    const float yawl = atan2f(naff[dbase + 3],  naff[dbase + 0]);
    const float yaw0 = atan2f(naff[dbase0 + 3], naff[dbase0 + 0]);
    // cos/sin(atan2(sin t, cos t)) == cos/sin(t)
    const float tt = yaw0 - yawl;
    const float cosd = cosf(tt), sind = sinf(tt);

    const float ego[8] = {mc0, demand, 0.0f, 0.0f, 1.0f, 0.0f, 0.0f, demand};
    const float fj[8]  = {mc, ov, dx, dy, cosd, sind, dist, demand};

    __shared__ float sh[64];
    __shared__ float qv[64];
    __shared__ float kv[64];

    // q = mlp2(ego)
    float h = qb1[t];
    for (int i = 0; i < 8; ++i) h = fmaf(ego[i], qW1[i * 64 + t], h);
    h = fmaxf(h, 0.0f);
    sh[t] = h;
    __syncthreads();
    float q2 = qb2[t];
    for (int i = 0; i < 64; ++i) q2 = fmaf(sh[i], qW2[i * 64 + t], q2);
    qv[t] = q2;
    __syncthreads();

    // k = mlp2(feat_j)
    float hk = kb1[t];
    for (int i = 0; i < 8; ++i) hk = fmaf(fj[i], kW1[i * 64 + t], hk);
    hk = fmaxf(hk, 0.0f);
    sh[t] = hk;
    __syncthreads();
    float k2 = kb2[t];
    for (int i = 0; i < 64; ++i) k2 = fmaf(sh[i], kW2[i * 64 + t], k2);
    kv[t] = k2;
    __syncthreads();

    // edge MLP on qk = [q, k] (128) -> 64 -> 1
    float he = eb1[t];
    for (int i = 0; i < 64; ++i) he = fmaf(qv[i], eW1[i * 64 + t], he);
    for (int i = 0; i < 64; ++i) he = fmaf(kv[i], eW1[(64 + i) * 64 + t], he);
    he = fmaxf(he, 0.0f);

    float part = he * eW2[t];
    for (int o = 32; o > 0; o >>= 1) part += __shfl_down(part, o);

    if (t == 0) {
        float r;
        if (l == 0) {
            r = 0.0f;  // logits[:,0] = -1e9 -> sigmoid -> 0
        } else {
            float logit = part + eb2[0];
            r = 1.0f / (1.0f + expf(-logit));
            r = fminf(fmaxf(r, 0.0f), 1.0f);
        }
        out[bl] = r;
    }
}

extern "C" void kernel_launch(void* const* d_in, const int* in_sizes, int n_in,
                              void* d_out, int out_size, void* d_ws, size_t ws_size,
                              hipStream_t stream) {
    const float* psm  = (const float*)d_in[0];
    const float* req  = (const float*)d_in[1];
    const float* naff = (const float*)d_in[2];
    // d_in[3] = record_len (unused; always == L)
    const float* qW1 = (const float*)d_in[4];
    const float* qb1 = (const float*)d_in[5];
    const float* qW2 = (const float*)d_in[6];
    const float* qb2 = (const float*)d_in[7];
    const float* kW1 = (const float*)d_in[8];
    const float* kb1 = (const float*)d_in[9];
    const float* kW2 = (const float*)d_in[10];
    const float* kb2 = (const float*)d_in[11];
    const float* eW1 = (const float*)d_in[12];
    const float* eb1 = (const float*)d_in[13];
    const float* eW2 = (const float*)d_in[14];
    const float* eb2 = (const float*)d_in[15];
    float* out  = (float*)d_out;
    float* sums = (float*)d_ws;

    hipLaunchKernelGGL(zero_kernel, dim3(2), dim3(256), 0, stream, sums);
    // 36 blocks/image * 256 thr = 9216 lanes -> exactly 16 px/thread; 4608 blocks total
    hipLaunchKernelGGL(heavy_kernel, dim3(36, NBL), dim3(256), 0, stream,
                       psm, req, naff, sums);
    hipLaunchKernelGGL(mlp_kernel, dim3(NBL), dim3(64), 0, stream,
                       sums, naff,
                       qW1, qb1, qW2, qb2, kW1, kb1, kW2, kb2,
                       eW1, eb1, eW2, eb2, out);
}